// Round 4
// baseline (138.525 us; speedup 1.0000x reference)
//
#include <hip/hip_runtime.h>
#include <math.h>

#define BB 16384
#define NSTEPS 32
#define HH 128
#define DTF (1.0f/32.0f)
#define SCALE 2.88539008177792681f   // 2*log2(e):  e^{2x} = 2^{SCALE*x}
#define LOG2E 1.44269504088896340f

typedef float v2f __attribute__((ext_vector_type(2)));
typedef float v8f __attribute__((ext_vector_type(8)));
typedef unsigned int v2u __attribute__((ext_vector_type(2)));

__device__ __forceinline__ v2f pk_fma(v2f a, v2f b, v2f c) {
    return __builtin_elementwise_fma(a, b, c);   // -> v_pk_fma_f32
}

// packed fast reciprocal: bit-trick estimate + 1 Newton. Valid x in [1, ~1e38].
// max rel err ~0.26% after Newton — well inside this problem's error budget.
__device__ __forceinline__ v2f pk_rcp1(v2f x) {
    v2u xb; __builtin_memcpy(&xb, &x, 8);
    v2u yb = (v2u){0x7EF311C3u, 0x7EF311C3u} - xb;
    v2f y;  __builtin_memcpy(&y, &yb, 8);
    v2f u = pk_fma(-x, y, (v2f){2.0f, 2.0f});    // 2 - x*y
    return y * u;
}

__device__ __forceinline__ float fexp2(float x) {
#if __has_builtin(__builtin_amdgcn_exp2f)
    return __builtin_amdgcn_exp2f(x);
#else
    float r; asm("v_exp_f32 %0, %1" : "=v"(r) : "v"(x)); return r;
#endif
}
__device__ __forceinline__ float frcp(float x) {
#if __has_builtin(__builtin_amdgcn_rcpf)
    return __builtin_amdgcn_rcpf(x);
#else
    float r; asm("v_rcp_f32 %0, %1" : "=v"(r) : "v"(x)); return r;
#endif
}
__device__ __forceinline__ float frsq(float x) {
#if __has_builtin(__builtin_amdgcn_rsqf)
    return __builtin_amdgcn_rsqf(x);
#else
    float r; asm("v_rsq_f32 %0, %1" : "=v"(r) : "v"(x)); return r;
#endif
}

// ---------------------------------------------------------------------------
// Transform kernel. Record per (i,j), 16 floats, (g,j) interleaved:
//  [0,1]=(S*gw0,S*jw0) [2,3]=(S*gw1,S*jw1) [4,5]=(S*gw2,S*jw2)
//  [6,7]=(S*gw3,S*jw3) [8,9]=(S*gb1,S*jb1) [10,11]=(-2g20,-2g21)
//  [12,13]=(-2g22,-2jW2) [14,15]=(e^{2jw0}, e^{-2jw0})
// ---------------------------------------------------------------------------
__global__ __launch_bounds__(HH) void xform_kernel(
    const float* __restrict__ gW1, const float* __restrict__ gb1,
    const float* __restrict__ gW2, const float* __restrict__ gb2,
    const float* __restrict__ jW1, const float* __restrict__ jb1,
    const float* __restrict__ jW2,
    float* __restrict__ recA, float* __restrict__ G)
{
    const int i = blockIdx.x;    // step
    const int j = threadIdx.x;   // hidden unit
    float* r = recA + ((size_t)(i*HH + j)) * 16;

    const float* gw = gW1 + (size_t)(i*HH + j)*4;
    const float* jw = jW1 + (size_t)(i*HH + j)*4;
    float jw0 = jw[0];
    r[0] = SCALE*gw[0]; r[1] = SCALE*jw0;
    r[2] = SCALE*gw[1]; r[3] = SCALE*jw[1];
    r[4] = SCALE*gw[2]; r[5] = SCALE*jw[2];
    r[6] = SCALE*gw[3]; r[7] = SCALE*jw[3];
    r[8] = SCALE*gb1[i*HH + j];
    r[9] = SCALE*jb1[i*HH + j];
    float g20 = gW2[i*3*HH + 0*HH + j];
    float g21 = gW2[i*3*HH + 1*HH + j];
    float g22 = gW2[i*3*HH + 2*HH + j];
    r[10] = -2.0f*g20; r[11] = -2.0f*g21;
    r[12] = -2.0f*g22; r[13] = -2.0f*jW2[i*HH + j];
    r[14] = exp2f( SCALE*jw0);
    r[15] = exp2f(-SCALE*jw0);

    __shared__ float sh[3*HH];
    sh[0*HH + j] = g20; sh[1*HH + j] = g21; sh[2*HH + j] = g22;
    __syncthreads();
    if (j < 3) {
        float s = gb2[i*3 + j];
        for (int t = 0; t < HH; ++t) s += sh[j*HH + t];
        G[i*4 + j] = s;
    }
}

// ---------------------------------------------------------------------------
// Main kernel. Block = 256 threads covering 128 batch elements x 2 j-halves
// (jhalf is wave-uniform -> weight loads stay scalar). Each thread does 64
// hidden units; halves combine via LDS. Four sigmoids per unit use packed
// bit-trick+Newton reciprocals; only 2 v_exp_f32 remain on the trans pipe.
// ---------------------------------------------------------------------------
__global__ __launch_bounds__(256) void step_kernel(
    const float* __restrict__ N, const float* __restrict__ X,
    const float* __restrict__ T, const float* __restrict__ dB,
    const float* __restrict__ recA, const float* __restrict__ G,
    float* __restrict__ C)
{
    const int tid  = threadIdx.x;
    const int i    = blockIdx.x >> 7;          // step (block-uniform)
    const int bblk = blockIdx.x & 127;
    const int bl   = tid & 127;                // local batch index
    const int jh   = tid >> 7;                 // j-half (wave-uniform)
    const int b    = bblk*128 + bl;
    const int ib   = i*BB + b;

    const float Ni = N[ib];
    const float x0 = X[(size_t)ib*3 + 0], x1 = X[(size_t)ib*3 + 1], x2 = X[(size_t)ib*3 + 2];

    const v8f* rec8 = (const v8f*)(recA + (size_t)i*HH*16) + (size_t)jh*128;

    const v2f Niv = {Ni, Ni};
    const v2f x0v = {x0, x0};
    const v2f x1v = {x1, x1};
    const v2f x2v = {x2, x2};
    const v2f one = {1.0f, 1.0f};
    const v2f c25 = {25.0f, 25.0f};

    v2f ga01 = {0.f, 0.f};   // (sum -2g20*rg, sum -2g21*rg)
    v2f g2a0 = {0.f, 0.f};   // (sum -2g22*rg, sum -2jW2*r0)
    v2f aPM  = {0.f, 0.f};   // (sum -2jW2*rp, sum -2jW2*rm)

#pragma unroll 4
    for (int t = 0; t < 64; ++t) {
        const v8f A  = rec8[2*t + 0];    // W1 rows, interleaved (g,j)
        const v8f Bv = rec8[2*t + 1];    // [gb,jb, -2g20,-2g21, -2g22,-2jW2, cp,cm]

        v2f acc = {Bv[0], Bv[1]};
        acc = pk_fma((v2f){A[0], A[1]}, Niv, acc);
        acc = pk_fma((v2f){A[2], A[3]}, x0v, acc);
        acc = pk_fma((v2f){A[4], A[5]}, x1v, acc);
        acc = pk_fma((v2f){A[6], A[7]}, x2v, acc);
        acc = __builtin_elementwise_min(acc, c25);   // upper clamp: keep exp2 finite

        const float eg = fexp2(acc[0]);
        const float eb = fexp2(acc[1]);

        v2f t01 = (v2f){eg, eb} + one;                              // (tg, t0)
        v2f tpm = pk_fma((v2f){eb, eb}, (v2f){Bv[6], Bv[7]}, one);  // (tp, tm)

        v2f r01 = pk_rcp1(t01);   // (1/tg, 1/t0)
        v2f rpm = pk_rcp1(tpm);   // (1/tp, 1/tm)

        ga01 = pk_fma((v2f){Bv[2], Bv[3]}, (v2f){r01[0], r01[0]}, ga01);
        g2a0 = pk_fma((v2f){Bv[4], Bv[5]}, r01, g2a0);
        aPM  = pk_fma((v2f){Bv[5], Bv[5]}, rpm, aPM);
    }

    __shared__ float sh[6][128];
    if (jh) {
        sh[0][bl] = ga01[0]; sh[1][bl] = ga01[1]; sh[2][bl] = g2a0[0];
        sh[3][bl] = g2a0[1]; sh[4][bl] = aPM[0];  sh[5][bl] = aPM[1];
    }
    __syncthreads();
    if (!jh) {
        const float g0 = G[i*4 + 0] + ga01[0] + sh[0][bl];
        const float g1 = G[i*4 + 1] + ga01[1] + sh[1][bl];
        const float g2 = G[i*4 + 2] + g2a0[0] + sh[2][bl];
        const float a0 = g2a0[1] + sh[3][bl];
        const float aP = aPM[0]  + sh[4][bl];
        const float aM = aPM[1]  + sh[5][bl];

        const float Np1 = N[ib + BB];
        const float d0 = dB[(size_t)ib*3 + 0], d1 = dB[(size_t)ib*3 + 1], d2 = dB[(size_t)ib*3 + 2];
        const float ti = T[i];

        const float gdx = g0*x0 + g1*x1 + g2*x2;          // grad_u . x
        const float ss  = x0*x0 + x1*x1 + x2*x2;          // x . x
        const float gdB = g0*d0 + g1*d1 + g2*d2;          // grad_u . dB
        const float xdB = x0*d0 + x1*d1 + x2*d2;          // x . dB

        const float k = 1.41421356237309505f * frsq(fmaf(0.1f*Ni, Ni, 1.0f));
        // kg^T (I+o)(I-o) dB = k*(g.dB - (x.x)*(g.x)*(x.dB))
        const float grad_bmm = k * (gdB - ss*gdx*xdB);

        const float dp = aP - a0;
        const float dm = aM - a0;

        // alpha = 0.3*sig(0.1 N), beta = 0.2*(1-sig(0.1 N))
        const float sig = frcp(1.0f + fexp2(-0.1f*LOG2E*Ni));
        const float alpha = 0.3f*sig;
        const float beta  = 0.2f - 0.2f*sig;

        const float dd = Np1 - Ni;                        // exact -1/0/+1
        const float jump = (dd > 0.5f) ? dp : ((dd < -0.5f) ? dm : 0.0f);

        const float c = grad_bmm - (alpha*dp + beta*dm)*DTF
                      - 0.05f*DTF*gdx - 0.01f*DTF*ti + jump;
        C[ib] = c;
    }
}

// ---------------------------------------------------------------------------
// Final kernel: u0 via r-MLP parallelized 16 lanes per batch element
// (shuffle-reduce), then 32-step affine scan on the group leader.
// ---------------------------------------------------------------------------
__global__ __launch_bounds__(256) void final_kernel(
    const float* __restrict__ N, const float* __restrict__ X,
    const float* __restrict__ rW1, const float* __restrict__ rb1,
    const float* __restrict__ rW2, const float* __restrict__ rb2,
    const float* __restrict__ C, float* __restrict__ out)
{
    const int gid = blockIdx.x*256 + threadIdx.x;
    const int b = gid >> 4;          // batch element
    const int p = gid & 15;          // 16-way split over hidden units

    const float n0 = N[b];
    const float x0 = X[(size_t)b*3 + 0], x1 = X[(size_t)b*3 + 1], x2 = X[(size_t)b*3 + 2];

    float accw = 0.f, accr = 0.f;
#pragma unroll
    for (int t = 0; t < 8; ++t) {
        const int j = p*8 + t;
        float pre = fmaf(rW1[j*4+0], n0, fmaf(rW1[j*4+1], x0,
                    fmaf(rW1[j*4+2], x1, fmaf(rW1[j*4+3], x2, rb1[j]))));
        float r  = frcp(1.0f + fexp2(SCALE*pre));
        float w2 = rW2[j];
        accw += w2;
        accr = fmaf(w2, r, accr);
    }
    accw += __shfl_down(accw, 8, 16);  accr += __shfl_down(accr, 8, 16);
    accw += __shfl_down(accw, 4, 16);  accr += __shfl_down(accr, 4, 16);
    accw += __shfl_down(accw, 2, 16);  accr += __shfl_down(accr, 2, 16);
    accw += __shfl_down(accw, 1, 16);  accr += __shfl_down(accr, 1, 16);

    if (p == 0) {
        float u = rb2[0] + accw - 2.0f*accr;    // rb2 + sum w2*tanh

        const float sfac = 1.0f + 0.05f*DTF;
#pragma unroll
        for (int i = 0; i < NSTEPS; ++i)
            u = fmaf(u, sfac, C[(size_t)i*BB + b]);
        out[b] = u;

        const int ib = NSTEPS*BB + b;
        out[BB + b] = fmaf(0.1f, N[ib], __cosf(X[(size_t)ib*3]));
    }
}

// ---------------------------------------------------------------------------
extern "C" void kernel_launch(void* const* d_in, const int* in_sizes, int n_in,
                              void* d_out, int out_size, void* d_ws, size_t ws_size,
                              hipStream_t stream)
{
    const float* N   = (const float*)d_in[0];
    const float* X   = (const float*)d_in[1];
    const float* T   = (const float*)d_in[2];
    const float* dB  = (const float*)d_in[3];
    const float* rW1 = (const float*)d_in[4];
    const float* rb1 = (const float*)d_in[5];
    const float* rW2 = (const float*)d_in[6];
    const float* rb2 = (const float*)d_in[7];
    const float* gW1 = (const float*)d_in[8];
    const float* gb1 = (const float*)d_in[9];
    const float* gW2 = (const float*)d_in[10];
    const float* gb2 = (const float*)d_in[11];
    const float* jW1 = (const float*)d_in[12];
    const float* jb1 = (const float*)d_in[13];
    const float* jW2 = (const float*)d_in[14];
    // jb2 (d_in[15]) cancels in dp/dm — unused.

    float* ws   = (float*)d_ws;
    float* C    = ws;                                  // 32*16384 floats
    float* recA = ws + (size_t)NSTEPS*BB;              // 32*128*16 floats
    float* G    = recA + (size_t)NSTEPS*HH*16;         // 128 floats
    float* out  = (float*)d_out;

    xform_kernel<<<NSTEPS, HH, 0, stream>>>(gW1, gb1, gW2, gb2, jW1, jb1, jW2, recA, G);
    step_kernel<<<NSTEPS*(BB/128), 256, 0, stream>>>(N, X, T, dB, recA, G, C);
    final_kernel<<<BB*16/256, 256, 0, stream>>>(N, X, rW1, rb1, rW2, rb2, C, out);
}

// Round 5
// 66.475 us; speedup vs baseline: 2.0838x; 2.0838x over previous
//
#include <hip/hip_runtime.h>
#include <math.h>

#define BB 16384
#define NSTEPS 32
#define HH 128
#define DTF (1.0f/32.0f)
#define SCALE 2.88539008177792681f   // 2*log2(e):  e^{2x} = 2^{SCALE*x}
#define LOG2E 1.44269504088896340f

typedef float v2f __attribute__((ext_vector_type(2)));
typedef float v8f __attribute__((ext_vector_type(8)));
typedef unsigned int v2u __attribute__((ext_vector_type(2)));

__device__ __forceinline__ v2f pk_fma(v2f a, v2f b, v2f c) {
    return __builtin_elementwise_fma(a, b, c);   // -> v_pk_fma_f32
}

// packed fast reciprocal: bit-trick estimate + 1 Newton. Valid x in [1, ~1e38].
// max rel err ~0.1% after Newton — inside this problem's error budget (R4: 0.031 abs).
__device__ __forceinline__ v2f pk_rcp1(v2f x) {
    v2u xb; __builtin_memcpy(&xb, &x, 8);
    v2u yb = (v2u){0x7EF311C3u, 0x7EF311C3u} - xb;
    v2f y;  __builtin_memcpy(&y, &yb, 8);
    v2f u = pk_fma(-x, y, (v2f){2.0f, 2.0f});    // 2 - x*y
    return y * u;
}

__device__ __forceinline__ float fexp2(float x) {
#if __has_builtin(__builtin_amdgcn_exp2f)
    return __builtin_amdgcn_exp2f(x);
#else
    float r; asm("v_exp_f32 %0, %1" : "=v"(r) : "v"(x)); return r;
#endif
}
__device__ __forceinline__ float frcp(float x) {
#if __has_builtin(__builtin_amdgcn_rcpf)
    return __builtin_amdgcn_rcpf(x);
#else
    float r; asm("v_rcp_f32 %0, %1" : "=v"(r) : "v"(x)); return r;
#endif
}
__device__ __forceinline__ float frsq(float x) {
#if __has_builtin(__builtin_amdgcn_rsqf)
    return __builtin_amdgcn_rsqf(x);
#else
    float r; asm("v_rsq_f32 %0, %1" : "=v"(r) : "v"(x)); return r;
#endif
}

// ---------------------------------------------------------------------------
// Transform kernel. Record per (i,j), 16 floats, (g,j) interleaved:
//  [0,1]=(S*gw0,S*jw0) [2,3]=(S*gw1,S*jw1) [4,5]=(S*gw2,S*jw2)
//  [6,7]=(S*gw3,S*jw3) [8,9]=(S*gb1,S*jb1) [10,11]=(-2g20,-2g21)
//  [12,13]=(-2g22,-2jW2) [14,15]=(e^{2jw0}, e^{-2jw0})
// ---------------------------------------------------------------------------
__global__ __launch_bounds__(HH) void xform_kernel(
    const float* __restrict__ gW1, const float* __restrict__ gb1,
    const float* __restrict__ gW2, const float* __restrict__ gb2,
    const float* __restrict__ jW1, const float* __restrict__ jb1,
    const float* __restrict__ jW2,
    float* __restrict__ recA, float* __restrict__ G)
{
    const int i = blockIdx.x;    // step
    const int j = threadIdx.x;   // hidden unit
    float* r = recA + ((size_t)(i*HH + j)) * 16;

    const float* gw = gW1 + (size_t)(i*HH + j)*4;
    const float* jw = jW1 + (size_t)(i*HH + j)*4;
    float jw0 = jw[0];
    r[0] = SCALE*gw[0]; r[1] = SCALE*jw0;
    r[2] = SCALE*gw[1]; r[3] = SCALE*jw[1];
    r[4] = SCALE*gw[2]; r[5] = SCALE*jw[2];
    r[6] = SCALE*gw[3]; r[7] = SCALE*jw[3];
    r[8] = SCALE*gb1[i*HH + j];
    r[9] = SCALE*jb1[i*HH + j];
    float g20 = gW2[i*3*HH + 0*HH + j];
    float g21 = gW2[i*3*HH + 1*HH + j];
    float g22 = gW2[i*3*HH + 2*HH + j];
    r[10] = -2.0f*g20; r[11] = -2.0f*g21;
    r[12] = -2.0f*g22; r[13] = -2.0f*jW2[i*HH + j];
    r[14] = exp2f( SCALE*jw0);
    r[15] = exp2f(-SCALE*jw0);

    __shared__ float sh[3*HH];
    sh[0*HH + j] = g20; sh[1*HH + j] = g21; sh[2*HH + j] = g22;
    __syncthreads();
    if (j < 3) {
        float s = gb2[i*3 + j];
        for (int t = 0; t < HH; ++t) s += sh[j*HH + t];
        G[i*4 + j] = s;
    }
}

// ---------------------------------------------------------------------------
// Main kernel. Block = 256 threads covering 128 batch elements x 2 j-halves.
// jh is forced into an SGPR via readfirstlane so the weight loads stay
// SCALAR (R4 lost this -> broadcast vector loads -> 2x regression).
// Four sigmoids per unit use packed bit-trick+Newton reciprocals; only
// 2 v_exp_f32 remain on the trans pipe.
// ---------------------------------------------------------------------------
__global__ __launch_bounds__(256) void step_kernel(
    const float* __restrict__ N, const float* __restrict__ X,
    const float* __restrict__ T, const float* __restrict__ dB,
    const float* __restrict__ recA, const float* __restrict__ G,
    float* __restrict__ C)
{
    const int tid  = threadIdx.x;
    const int i    = blockIdx.x >> 7;          // step (block-uniform)
    const int bblk = blockIdx.x & 127;
    const int bl   = tid & 127;                // local batch index
    const int jh   = __builtin_amdgcn_readfirstlane(tid >> 7);  // wave-uniform -> SGPR
    const int b    = bblk*128 + bl;
    const int ib   = i*BB + b;

    const float Ni = N[ib];
    const float x0 = X[(size_t)ib*3 + 0], x1 = X[(size_t)ib*3 + 1], x2 = X[(size_t)ib*3 + 2];

    const v8f* rec8 = (const v8f*)(recA + (size_t)i*HH*16) + (size_t)jh*128;

    const v2f Niv = {Ni, Ni};
    const v2f x0v = {x0, x0};
    const v2f x1v = {x1, x1};
    const v2f x2v = {x2, x2};
    const v2f one = {1.0f, 1.0f};
    const v2f c25 = {25.0f, 25.0f};

    v2f ga01 = {0.f, 0.f};   // (sum -2g20*rg, sum -2g21*rg)
    v2f g2a0 = {0.f, 0.f};   // (sum -2g22*rg, sum -2jW2*r0)
    v2f aPM  = {0.f, 0.f};   // (sum -2jW2*rp, sum -2jW2*rm)

#pragma unroll 4
    for (int t = 0; t < 64; ++t) {
        const v8f A  = rec8[2*t + 0];    // W1 rows, interleaved (g,j)
        const v8f Bv = rec8[2*t + 1];    // [gb,jb, -2g20,-2g21, -2g22,-2jW2, cp,cm]

        v2f acc = {Bv[0], Bv[1]};
        acc = pk_fma((v2f){A[0], A[1]}, Niv, acc);
        acc = pk_fma((v2f){A[2], A[3]}, x0v, acc);
        acc = pk_fma((v2f){A[4], A[5]}, x1v, acc);
        acc = pk_fma((v2f){A[6], A[7]}, x2v, acc);
        acc = __builtin_elementwise_min(acc, c25);   // keep exp2 finite (rcp1 domain)

        const float eg = fexp2(acc[0]);
        const float eb = fexp2(acc[1]);

        v2f t01 = (v2f){eg, eb} + one;                              // (tg, t0)
        v2f tpm = pk_fma((v2f){eb, eb}, (v2f){Bv[6], Bv[7]}, one);  // (tp, tm)

        v2f r01 = pk_rcp1(t01);   // (1/tg, 1/t0)
        v2f rpm = pk_rcp1(tpm);   // (1/tp, 1/tm)

        ga01 = pk_fma((v2f){Bv[2], Bv[3]}, (v2f){r01[0], r01[0]}, ga01);
        g2a0 = pk_fma((v2f){Bv[4], Bv[5]}, r01, g2a0);
        aPM  = pk_fma((v2f){Bv[5], Bv[5]}, rpm, aPM);
    }

    __shared__ float sh[6][128];
    if (jh) {
        sh[0][bl] = ga01[0]; sh[1][bl] = ga01[1]; sh[2][bl] = g2a0[0];
        sh[3][bl] = g2a0[1]; sh[4][bl] = aPM[0];  sh[5][bl] = aPM[1];
    }
    __syncthreads();
    if (!jh) {
        const float g0 = G[i*4 + 0] + ga01[0] + sh[0][bl];
        const float g1 = G[i*4 + 1] + ga01[1] + sh[1][bl];
        const float g2 = G[i*4 + 2] + g2a0[0] + sh[2][bl];
        const float a0 = g2a0[1] + sh[3][bl];
        const float aP = aPM[0]  + sh[4][bl];
        const float aM = aPM[1]  + sh[5][bl];

        const float Np1 = N[ib + BB];
        const float d0 = dB[(size_t)ib*3 + 0], d1 = dB[(size_t)ib*3 + 1], d2 = dB[(size_t)ib*3 + 2];
        const float ti = T[i];

        const float gdx = g0*x0 + g1*x1 + g2*x2;          // grad_u . x
        const float ss  = x0*x0 + x1*x1 + x2*x2;          // x . x
        const float gdB = g0*d0 + g1*d1 + g2*d2;          // grad_u . dB
        const float xdB = x0*d0 + x1*d1 + x2*d2;          // x . dB

        const float k = 1.41421356237309505f * frsq(fmaf(0.1f*Ni, Ni, 1.0f));
        // kg^T (I+o)(I-o) dB = k*(g.dB - (x.x)*(g.x)*(x.dB))
        const float grad_bmm = k * (gdB - ss*gdx*xdB);

        const float dp = aP - a0;
        const float dm = aM - a0;

        // alpha = 0.3*sig(0.1 N), beta = 0.2*(1-sig(0.1 N))
        const float sig = frcp(1.0f + fexp2(-0.1f*LOG2E*Ni));
        const float alpha = 0.3f*sig;
        const float beta  = 0.2f - 0.2f*sig;

        const float dd = Np1 - Ni;                        // exact -1/0/+1
        const float jump = (dd > 0.5f) ? dp : ((dd < -0.5f) ? dm : 0.0f);

        const float c = grad_bmm - (alpha*dp + beta*dm)*DTF
                      - 0.05f*DTF*gdx - 0.01f*DTF*ti + jump;
        C[ib] = c;
    }
}

// ---------------------------------------------------------------------------
// Final kernel: u0 via r-MLP parallelized 16 lanes per batch element
// (shuffle-reduce), then 32-step affine scan on the group leader.
// ---------------------------------------------------------------------------
__global__ __launch_bounds__(256) void final_kernel(
    const float* __restrict__ N, const float* __restrict__ X,
    const float* __restrict__ rW1, const float* __restrict__ rb1,
    const float* __restrict__ rW2, const float* __restrict__ rb2,
    const float* __restrict__ C, float* __restrict__ out)
{
    const int gid = blockIdx.x*256 + threadIdx.x;
    const int b = gid >> 4;          // batch element
    const int p = gid & 15;          // 16-way split over hidden units

    const float n0 = N[b];
    const float x0 = X[(size_t)b*3 + 0], x1 = X[(size_t)b*3 + 1], x2 = X[(size_t)b*3 + 2];

    float accw = 0.f, accr = 0.f;
#pragma unroll
    for (int t = 0; t < 8; ++t) {
        const int j = p*8 + t;
        float pre = fmaf(rW1[j*4+0], n0, fmaf(rW1[j*4+1], x0,
                    fmaf(rW1[j*4+2], x1, fmaf(rW1[j*4+3], x2, rb1[j]))));
        float r  = frcp(1.0f + fexp2(SCALE*pre));
        float w2 = rW2[j];
        accw += w2;
        accr = fmaf(w2, r, accr);
    }
    accw += __shfl_down(accw, 8, 16);  accr += __shfl_down(accr, 8, 16);
    accw += __shfl_down(accw, 4, 16);  accr += __shfl_down(accr, 4, 16);
    accw += __shfl_down(accw, 2, 16);  accr += __shfl_down(accr, 2, 16);
    accw += __shfl_down(accw, 1, 16);  accr += __shfl_down(accr, 1, 16);

    if (p == 0) {
        float u = rb2[0] + accw - 2.0f*accr;    // rb2 + sum w2*tanh

        const float sfac = 1.0f + 0.05f*DTF;
#pragma unroll
        for (int i = 0; i < NSTEPS; ++i)
            u = fmaf(u, sfac, C[(size_t)i*BB + b]);
        out[b] = u;

        const int ib = NSTEPS*BB + b;
        out[BB + b] = fmaf(0.1f, N[ib], __cosf(X[(size_t)ib*3]));
    }
}

// ---------------------------------------------------------------------------
extern "C" void kernel_launch(void* const* d_in, const int* in_sizes, int n_in,
                              void* d_out, int out_size, void* d_ws, size_t ws_size,
                              hipStream_t stream)
{
    const float* N   = (const float*)d_in[0];
    const float* X   = (const float*)d_in[1];
    const float* T   = (const float*)d_in[2];
    const float* dB  = (const float*)d_in[3];
    const float* rW1 = (const float*)d_in[4];
    const float* rb1 = (const float*)d_in[5];
    const float* rW2 = (const float*)d_in[6];
    const float* rb2 = (const float*)d_in[7];
    const float* gW1 = (const float*)d_in[8];
    const float* gb1 = (const float*)d_in[9];
    const float* gW2 = (const float*)d_in[10];
    const float* gb2 = (const float*)d_in[11];
    const float* jW1 = (const float*)d_in[12];
    const float* jb1 = (const float*)d_in[13];
    const float* jW2 = (const float*)d_in[14];
    // jb2 (d_in[15]) cancels in dp/dm — unused.

    float* ws   = (float*)d_ws;
    float* C    = ws;                                  // 32*16384 floats
    float* recA = ws + (size_t)NSTEPS*BB;              // 32*128*16 floats
    float* G    = recA + (size_t)NSTEPS*HH*16;         // 128 floats
    float* out  = (float*)d_out;

    xform_kernel<<<NSTEPS, HH, 0, stream>>>(gW1, gb1, gW2, gb2, jW1, jb1, jW2, recA, G);
    step_kernel<<<NSTEPS*(BB/128), 256, 0, stream>>>(N, X, T, dB, recA, G, C);
    final_kernel<<<BB*16/256, 256, 0, stream>>>(N, X, rW1, rb1, rW2, rb2, C, out);
}